// Round 3
// baseline (257.661 us; speedup 1.0000x reference)
//
#include <hip/hip_runtime.h>
#include <math.h>

// Problem constants (from reference)
#define A_ 3
#define H_ 128
#define W_ 128
#define C_ 2
#define ATTRS 7
#define B_ 64
#define CELLS_PER_BATCH (A_*H_*W_)          // 49152
#define TOTAL_CELLS (B_*CELLS_PER_BATCH)    // 3145728

#define NBLK 768
#define NTHR 256
#define NWAVES (NBLK*4)                     // 3072
#define CELLS_PER_WAVE 1024                 // 48 wave-regions per batch
#define CHUNK 256                           // cells per wave-chunk (4 cells/lane)
#define NCHUNK 4
#define NSLOTS 32

// ws float layout:
//   [0..192)    partial sums, index = m*NSLOTS + slot   (m in [0,6))
//   [200]       completion counter (uint bits)
//   [256..1280) per-batch data: 16 floats/batch =
//               t0:[cx,cy,bw,bh][areaT,t5,codef,0]  t1: same
#define WS_CNT   200
#define WS_BATCH 256

__global__ __launch_bounds__(256) void prep_k(
    const float* __restrict__ boxes,
    const int*   __restrict__ labels,
    const float* __restrict__ areas,
    float* __restrict__ ws)
{
    const int tid = threadIdx.x;
    ws[tid] = 0.0f;                 // zero slots [0..192) and counter [200]
    if (tid < B_) {
        const int b = tid;
        float o16[16];
        #pragma unroll
        for (int t = 0; t < 2; ++t) {
            const float x1 = boxes[b*8 + t*4 + 0];
            const float y1 = boxes[b*8 + t*4 + 1];
            const float x2 = boxes[b*8 + t*4 + 2];
            const float y2 = boxes[b*8 + t*4 + 3];
            const float cx = (x1 + x2) * 0.5f, cy = (y1 + y2) * 0.5f;
            const float bw = x2 - x1,          bh = y2 - y1;
            const float at = (bw - cx) * (bh - cy);   // reference "area_t" quirk
            const float ar = areas[b*2 + t];
            const float d0 = fabsf(10440.f - ar);
            const float d1 = fabsf(30888.f - ar);
            const float d2 = fabsf(121598.f - ar);
            int ba = 0; float bd = d0;
            if (d1 < bd) { ba = 1; bd = d1; }
            if (d2 < bd) { ba = 2; }
            const int cX = (int)((bw - cx) * 0.125f); // trunc
            const int cY = (int)((bh - cy) * 0.125f);
            const int code = ba * (H_*W_) + cX * W_ + cY;   // flattened (a,i,j)
            const int lab = labels[b*2 + t];
            const float t5 = (t == 0) ? (lab == 1 ? 1.f : 0.f)
                                      : (lab == 2 ? 1.f : 0.f);
            o16[t*8+0]=cx; o16[t*8+1]=cy; o16[t*8+2]=bw; o16[t*8+3]=bh;
            o16[t*8+4]=at; o16[t*8+5]=t5; o16[t*8+6]=(float)code; o16[t*8+7]=0.f;
        }
        #pragma unroll
        for (int k = 0; k < 16; ++k) ws[WS_BATCH + b*16 + k] = o16[k];
    }
}

__global__ __launch_bounds__(NTHR) void yolo_main_k(
    const float* __restrict__ outp,
    float* __restrict__ ws,
    float* __restrict__ o)
{
    const int tid  = threadIdx.x;
    const int lane = tid & 63;
    const int wv   = (blockIdx.x << 2) | (tid >> 6);   // wave id [0,3072)
    const int b    = wv / 48;                          // batch (uniform per wave)
    const int rbase = (wv - b * 48) * CELLS_PER_WAVE;  // within-batch base cell

    // batch constants (written by prep_k; kernel-boundary makes them coherent)
    const float4* wsb = (const float4*)(ws + WS_BATCH) + b * 4;
    const float4 p0 = wsb[0], q0 = wsb[1];   // t0: cx,cy,bw,bh | at,t5,code,0
    const float4 p1 = wsb[2], q1 = wsb[3];   // t1
    const int code0 = (int)q0.z, code1 = (int)q1.z;
    const float at0 = q0.x, at1 = q1.x;

    // global float4 base of this wave's 1024-cell region (1792 float4s)
    const float4* gbase = (const float4*)outp
                        + (size_t)(b * CELLS_PER_BATCH + rbase) * ATTRS / 4;

    float4 A[7], Bf[7];
    #pragma unroll
    for (int i = 0; i < 7; ++i) A[i] = gbase[7*lane + i];   // chunk 0

    float accX=0.f, accY=0.f, accW=0.f, accH=0.f, accC=0.f, accK=0.f;

    #pragma unroll
    for (int k = 0; k < NCHUNK; ++k) {
        if (k < NCHUNK-1) {                    // prefetch next chunk into regs
            const float4* gn = gbase + 448*(k+1);
            #pragma unroll
            for (int i = 0; i < 7; ++i) Bf[i] = gn[7*lane + i];
        }
        const int rc = rbase + CHUNK*k + 4*lane;   // first of 4 cells (in-batch)
        const int i0 = (rc >> 7) & 127;            // constant across the 4 cells
        const float fi  = (float)i0;
        const float fj0 = (float)(rc & 127);
        const float* f = (const float*)A;

        #pragma unroll
        for (int cc = 0; cc < 4; ++cc) {
            const float xr  = f[7*cc+0], yr = f[7*cc+1];
            const float w   = f[7*cc+2], h  = f[7*cc+3];
            const float conf= f[7*cc+4], c0 = f[7*cc+5], c1 = f[7*cc+6];
            const float fj = fj0 + (float)cc;
            const float x = xr - fi, y = yr - fj;
            const float hw = 0.5f*w, hh = 0.5f*h;
            const float px1 = x - hw, px2 = x + hw;
            const float py1 = y - hh, py2 = y + hh;
            const float areaP = w * h;

            // reference quirk: (tx1,ty1,tx2,ty2) = (cx,cy,bw,bh)
            const float ix0 = fmaxf(fminf(px2, p0.z) - fmaxf(px1, p0.x), 0.f);
            const float iy0 = fmaxf(fminf(py2, p0.w) - fmaxf(py1, p0.y), 0.f);
            const float in0 = ix0 * iy0;
            const float ix1 = fmaxf(fminf(px2, p1.z) - fmaxf(px1, p1.x), 0.f);
            const float iy1 = fmaxf(fminf(py2, p1.w) - fmaxf(py1, p1.y), 0.f);
            const float in1 = ix1 * iy1;

            const int r = rc + cc;
            const bool e0 = (r == code0), e1 = (r == code1);
            const bool exact = e0 || e1;
            // iou > 0.5  <=>  3*in > areaP + at  (denominator positive; margin
            // is 3 vs >=6400, so no rounding-flip risk vs the divide form)
            const bool sup = (!exact) &&
                ((3.f*in0 > areaP + at0) || (3.f*in1 > areaP + at1));

            if (exact) {                        // <=2 cells/batch; execz-skipped
                const float cx = e1 ? p1.x : p0.x, cy = e1 ? p1.y : p0.y;
                const float bw = e1 ? p1.z : p0.z, bh = e1 ? p1.w : p0.w;
                const float t5 = e1 ? q1.y : q0.y;
                const float dx = x - (cx - fi); accX += dx * dx;
                const float dy = y - (cy - fj); accY += dy * dy;
                const float dw = w - bw;        accW += dw * dw;
                const float dh = h - bh;        accH += dh * dh;
                accC += fmaxf(__logf(conf), -100.f);          // tConf = 1
                if (t5 != 0.f)
                    accK += fmaxf(__logf(c0), -100.f) + fmaxf(__logf(c1), -100.f);
                else
                    accK += fmaxf(__logf(1.f - c0), -100.f)
                          + fmaxf(__logf(1.f - c1), -100.f);
            } else if (!sup) {
                accC += fmaxf(__logf(1.f - conf), -100.f);    // tConf = 0
            }
        }
        #pragma unroll
        for (int i = 0; i < 7; ++i) A[i] = Bf[i];   // rotate (SSA-coalesced)
    }

    // ---- wave shuffle reduction -> 6 atomics per wave (32-slot scatter) ----
    float v[6] = {accX, accY, accW, accH, accC, accK};
    #pragma unroll
    for (int m = 0; m < 6; ++m) {
        #pragma unroll
        for (int off = 32; off > 0; off >>= 1) v[m] += __shfl_down(v[m], off, 64);
    }
    int lastf = 0;
    if (lane == 0) {
        const int slot = wv & (NSLOTS - 1);
        #pragma unroll
        for (int m = 0; m < 6; ++m) atomicAdd(&ws[m*NSLOTS + slot], v[m]);
        __threadfence();
        lastf = (atomicAdd((unsigned*)(ws + WS_CNT), 1u) == (unsigned)(NWAVES-1));
    }
    lastf = __shfl(lastf, 0, 64);
    if (!lastf) return;

    // ---- last wave finalizes: read 192 slots (3/lane), in-wave reduce ----
    float sa = atomicAdd(&ws[lane],       0.f);   // m = lane/32      (0 or 1)
    float sb = atomicAdd(&ws[64 + lane],  0.f);   // m = 2 + lane/32
    float sc = atomicAdd(&ws[128 + lane], 0.f);   // m = 4 + lane/32
    #pragma unroll
    for (int off = 16; off > 0; off >>= 1) {      // reduce within 32-lane halves
        sa += __shfl_xor(sa, off, 64);
        sb += __shfl_xor(sb, off, 64);
        sc += __shfl_xor(sc, off, 64);
    }
    const float m1 = __shfl(sa, 32, 64);
    const float m3 = __shfl(sb, 32, 64);
    const float m5 = __shfl(sc, 32, 64);
    if (lane == 0) {
        const float N = (float)TOTAL_CELLS;
        const float xL = sa / N, yL = m1 / N;
        const float wL = sb / N, hL = m3 / N;
        const float confL = -sc / N;
        const float clsL  = -m5 / (N * (float)C_);
        o[0] = 2.5f * (xL + yL) + 2.5f * (wL + hL) + confL + clsL;
        o[1] = xL; o[2] = yL; o[3] = wL; o[4] = hL; o[5] = confL; o[6] = clsL;
    }
}

extern "C" void kernel_launch(void* const* d_in, const int* in_sizes, int n_in,
                              void* d_out, int out_size, void* d_ws, size_t ws_size,
                              hipStream_t stream) {
    const float* outp   = (const float*)d_in[0];
    const float* boxes  = (const float*)d_in[1];
    const int*   labels = (const int*)d_in[2];
    const float* areas  = (const float*)d_in[3];
    float* ws = (float*)d_ws;
    float* o  = (float*)d_out;

    prep_k<<<1, 256, 0, stream>>>(boxes, labels, areas, ws);
    yolo_main_k<<<NBLK, NTHR, 0, stream>>>(outp, ws, o);
}

// Round 4
// 150.897 us; speedup vs baseline: 1.7075x; 1.7075x over previous
//
#include <hip/hip_runtime.h>
#include <math.h>

// Problem constants (from reference)
#define A_ 3
#define H_ 128
#define W_ 128
#define C_ 2
#define ATTRS 7
#define B_ 64
#define CELLS_PER_BATCH (A_*H_*W_)          // 49152
#define TOTAL_CELLS (B_*CELLS_PER_BATCH)    // 3145728

#define NBLK 3072
#define NTHR 256
#define CELLS_PER_BLK 1024                  // one 28 KB LDS tile per block
#define BLKS_PER_BATCH 48                   // 49152/1024 -> b uniform per block
#define NSLOTS 32

// ws float layout: [0..192) partial sums, index = m*NSLOTS + slot, m in [0,6)
__global__ __launch_bounds__(192) void zero_ws_k(float* ws) {
    ws[threadIdx.x] = 0.0f;
}

__global__ __launch_bounds__(NTHR) void yolo_main_k(
    const float* __restrict__ outp,
    const float* __restrict__ boxes,
    const int*   __restrict__ labels,
    const float* __restrict__ areas,
    float* __restrict__ ws)
{
    __shared__ float4 s_tile[1792];     // 1024 cells * 7 floats = 28672 B
    __shared__ float  s_red[4][6];
    const int tid = threadIdx.x;

    // ---- stage tile: 7 fully-coalesced float4 loads (issued up front) ----
    const float4* gp = (const float4*)outp + (size_t)blockIdx.x * 1792;
    float4 L0 = gp[tid], L1 = gp[tid+256], L2 = gp[tid+512], L3 = gp[tid+768];
    float4 L4 = gp[tid+1024], L5 = gp[tid+1280], L6 = gp[tid+1536];

    // ---- per-block batch constants (uniform; overlaps load latency) ----
    const int b  = blockIdx.x / BLKS_PER_BATCH;
    const int r0 = (blockIdx.x % BLKS_PER_BATCH) * CELLS_PER_BLK;
    float cxA[2], cyA[2], bwA[2], bhA[2], atA[2], t5A[2]; int codeA[2];
    #pragma unroll
    for (int t = 0; t < 2; ++t) {
        const float x1 = boxes[b*8 + t*4 + 0];
        const float y1 = boxes[b*8 + t*4 + 1];
        const float x2 = boxes[b*8 + t*4 + 2];
        const float y2 = boxes[b*8 + t*4 + 3];
        const float cx = (x1 + x2) * 0.5f, cy = (y1 + y2) * 0.5f;
        const float bw = x2 - x1,          bh = y2 - y1;
        cxA[t]=cx; cyA[t]=cy; bwA[t]=bw; bhA[t]=bh;
        atA[t] = (bw - cx) * (bh - cy);        // reference "area_t" quirk
        const float ar = areas[b*2 + t];
        const float d0 = fabsf(10440.f - ar);
        const float d1 = fabsf(30888.f - ar);
        const float d2 = fabsf(121598.f - ar);
        int ba = 0; float bd = d0;
        if (d1 < bd) { ba = 1; bd = d1; }
        if (d2 < bd) { ba = 2; }
        const int cX = (int)((bw - cx) * 0.125f);   // trunc toward 0
        const int cY = (int)((bh - cy) * 0.125f);
        codeA[t] = ba * (H_*W_) + cX * W_ + cY;     // flattened (a,i,j)
        const int lab = labels[b*2 + t];
        t5A[t] = (t == 0) ? (lab == 1 ? 1.f : 0.f) : (lab == 2 ? 1.f : 0.f);
    }

    // ---- write tile to LDS, single barrier ----
    s_tile[tid]      = L0; s_tile[tid+256]  = L1; s_tile[tid+512]  = L2;
    s_tile[tid+768]  = L3; s_tile[tid+1024] = L4; s_tile[tid+1280] = L5;
    s_tile[tid+1536] = L6;
    __syncthreads();

    float accX=0.f, accY=0.f, accW=0.f, accH=0.f, accC=0.f, accK=0.f;

    #pragma unroll
    for (int g = 0; g < 4; ++g) {
        const int c = tid + 256*g;              // cell within tile
        const int r = r0 + c;                   // within-batch flat (a,i,j)
        const float* sp = ((const float*)s_tile) + c*ATTRS; // stride-7: 2-way alias (free)
        const float xr = sp[0], yr = sp[1], w = sp[2], h = sp[3];
        const float conf = sp[4], c0 = sp[5], c1 = sp[6];

        const float fi = (float)((r >> 7) & 127);
        const float fj = (float)(r & 127);
        const float x = xr - fi, y = yr - fj;
        const float hw = 0.5f*w, hh = 0.5f*h;
        const float px1 = x - hw, px2 = x + hw;
        const float py1 = y - hh, py2 = y + hh;
        const float areaP = w * h;

        // reference quirk: (tx1,ty1,tx2,ty2) = (cx,cy,bw,bh)
        const float ix0 = fmaxf(fminf(px2, bwA[0]) - fmaxf(px1, cxA[0]), 0.f);
        const float iy0 = fmaxf(fminf(py2, bhA[0]) - fmaxf(py1, cyA[0]), 0.f);
        const float in0 = ix0 * iy0;
        const float ix1 = fmaxf(fminf(px2, bwA[1]) - fmaxf(px1, cxA[1]), 0.f);
        const float iy1 = fmaxf(fminf(py2, bhA[1]) - fmaxf(py1, cyA[1]), 0.f);
        const float in1 = ix1 * iy1;

        const bool e0 = (r == codeA[0]), e1 = (r == codeA[1]);
        const bool exact = e0 || e1;
        // iou > 0.5  <=>  3*in > areaP + at  (denom > 0; at >= 6400 vs in < 1:
        // no rounding-flip risk vs the divide form)
        const bool sup = (!exact) &&
            ((3.f*in0 > areaP + atA[0]) || (3.f*in1 > areaP + atA[1]));

        if (exact) {                            // <=2 cells per batch
            const int t = e1 ? 1 : 0;           // .at[].set: t=1 overwrites t=0
            const float dx = x - (cxA[t] - fi); accX += dx * dx;
            const float dy = y - (cyA[t] - fj); accY += dy * dy;
            const float dw = w - bwA[t];        accW += dw * dw;
            const float dh = h - bhA[t];        accH += dh * dh;
            accC += fmaxf(__logf(conf), -100.f);            // tConf = 1
            if (t5A[t] != 0.f)                              // both cls channels
                accK += fmaxf(__logf(c0), -100.f) + fmaxf(__logf(c1), -100.f);
            else
                accK += fmaxf(__logf(1.f - c0), -100.f)
                      + fmaxf(__logf(1.f - c1), -100.f);
        } else if (!sup) {
            accC += fmaxf(__logf(1.f - conf), -100.f);      // tConf = 0
        }
    }

    // ---- wave shuffle -> LDS block reduce -> 6 scatter atomics ----
    float v[6] = {accX, accY, accW, accH, accC, accK};
    #pragma unroll
    for (int m = 0; m < 6; ++m) {
        #pragma unroll
        for (int off = 32; off > 0; off >>= 1) v[m] += __shfl_down(v[m], off, 64);
    }
    const int wid = tid >> 6;
    if ((tid & 63) == 0) {
        #pragma unroll
        for (int m = 0; m < 6; ++m) s_red[wid][m] = v[m];
    }
    __syncthreads();
    if (tid < 6) {
        const float s = s_red[0][tid] + s_red[1][tid] + s_red[2][tid] + s_red[3][tid];
        atomicAdd(&ws[tid * NSLOTS + (blockIdx.x & (NSLOTS - 1))], s);
    }
    // NO completion counter, NO __threadfence — finalize is a separate dispatch.
}

__global__ __launch_bounds__(64) void finalize_k(const float* __restrict__ ws,
                                                 float* __restrict__ o)
{
    const int lane = threadIdx.x & 63;
    float sa = ws[lane];            // m = 0 (lanes 0..31) / m = 1 (lanes 32..63)
    float sb = ws[64 + lane];       // m = 2 / 3
    float sc = ws[128 + lane];      // m = 4 / 5
    #pragma unroll
    for (int off = 16; off > 0; off >>= 1) {   // reduce within 32-lane halves
        sa += __shfl_xor(sa, off, 64);
        sb += __shfl_xor(sb, off, 64);
        sc += __shfl_xor(sc, off, 64);
    }
    const float m1 = __shfl(sa, 32, 64);
    const float m3 = __shfl(sb, 32, 64);
    const float m5 = __shfl(sc, 32, 64);
    if (lane == 0) {
        const float N = (float)TOTAL_CELLS;
        const float xL = sa / N, yL = m1 / N;
        const float wL = sb / N, hL = m3 / N;
        const float confL = -sc / N;
        const float clsL  = -m5 / (N * (float)C_);
        o[0] = 2.5f * (xL + yL) + 2.5f * (wL + hL) + confL + clsL;
        o[1] = xL; o[2] = yL; o[3] = wL; o[4] = hL; o[5] = confL; o[6] = clsL;
    }
}

extern "C" void kernel_launch(void* const* d_in, const int* in_sizes, int n_in,
                              void* d_out, int out_size, void* d_ws, size_t ws_size,
                              hipStream_t stream) {
    const float* outp   = (const float*)d_in[0];
    const float* boxes  = (const float*)d_in[1];
    const int*   labels = (const int*)d_in[2];
    const float* areas  = (const float*)d_in[3];
    float* ws = (float*)d_ws;
    float* o  = (float*)d_out;

    zero_ws_k<<<1, 192, 0, stream>>>(ws);
    yolo_main_k<<<NBLK, NTHR, 0, stream>>>(outp, boxes, labels, areas, ws);
    finalize_k<<<1, 64, 0, stream>>>(ws, o);
}